// Round 9
// baseline (131.181 us; speedup 1.0000x reference)
//
#include <hip/hip_runtime.h>
#include <hip/hip_fp16.h>

// 21-qubit batched (B=4) state-vector simulator, 6 split passes + reduce.
// R9: occupancy push. Tiles 2^13 amps (32KB f32 LDS), 1024 blocks x 512 thr,
// 16 amps/thread -> 4 blocks/CU co-resident = 8 waves/SIMD (max), VGPR<=64
// via __launch_bounds__(512,8). Bipartition: L = {g0..g12} (links (12,11)..(1,0),
// RYs g1..g11), H = {g0..g3,g12..g20} (wrap + RYs g0,g12..g20 + next-layer links
// (20,19)..(13,12)). Per-RT GF(2)-linear LDS layouts: reads always b128,
// writes paired b64, <=2-way banks via granule swizzle PH3.
// fp16 global state (16MB), qubit q <-> g-bit (20-q). XCD batch affinity.

#define NQ 21
#define SHC(q) __shfl(cv, (q)), __shfl(sv, (q))

__device__ __forceinline__ int PH3(int g) {   // 11-bit granule swizzle
  return g ^ ((g >> 3) & 7) ^ ((g >> 6) & 7) ^ ((g >> 9) & 7);
}

template<int Q>
__device__ __forceinline__ void ry16(float* v, float c, float s) {
#pragma unroll
  for (int k = 0; k < 8; ++k) {
    int l0 = ((k >> Q) << (Q + 1)) | (k & ((1 << Q) - 1));
    int l1 = l0 | (1 << Q);
    float a0 = v[l0], a1 = v[l1];
    v[l0] = c * a0 - s * a1;
    v[l1] = s * a0 + c * a1;
  }
}

template<int C, int T>
__device__ __forceinline__ void cnot16(float* v) {
  constexpr int lo = (C < T) ? C : T;
  constexpr int hi = (C < T) ? T : C;
#pragma unroll
  for (int k = 0; k < 4; ++k) {
    int i1 = ((k >> lo) << (lo + 1)) | (k & ((1 << lo) - 1));
    int i2 = ((i1 >> hi) << (hi + 1)) | (i1 & ((1 << hi) - 1));
    int a = i2 | (1 << C);
    int b = a | (1 << T);
    float tmp = v[a]; v[a] = v[b]; v[b] = tmp;
  }
}

__device__ __forceinline__ void ld4(const uint2* __restrict__ g, int idx, float* dst) {
  uint2 r = g[idx];
  __half2 h0 = *reinterpret_cast<__half2*>(&r.x);
  __half2 h1 = *reinterpret_cast<__half2*>(&r.y);
  float2 f0 = __half22float2(h0), f1 = __half22float2(h1);
  dst[0] = f0.x; dst[1] = f0.y; dst[2] = f1.x; dst[3] = f1.y;
}
__device__ __forceinline__ unsigned pkh(float a, float b) {
  __half2 h = __floats2half2_rn(a, b);
  return *reinterpret_cast<unsigned*>(&h);
}
__device__ __forceinline__ void st2(float* s, int sl, float a, float b) {
  int ps = (PH3(sl >> 2) << 2) | (sl & 3);
  *reinterpret_cast<float2*>(s + ps) = float2{a, b};
}

// H-pass local granule -> global granule (t = g4..g11; lg: l2,l3 | l4..l12)
#define GH(lg) (((lg) & 3) | (t << 2) | (((lg) >> 2) << 10))

// ---------------- L pass: tile g0..g12, t = g13..g20 (8 bits) ----------------
// Sweeps: S1{a0,a1,a11,a12} -> S2{a8..a11} -> S3{a5..a8} -> S4{a2..a5} -> S5{a0,a1,a2,a8}
template<bool INIT>
__global__ __launch_bounds__(512, 8) void k_L(const float* __restrict__ x,
                                              const float* __restrict__ w,
                                              unsigned long long stp) {
  __shared__ __align__(16) float s[8192];
  float4* s4 = reinterpret_cast<float4*>(s);
  const int tid = threadIdx.x, lane = tid & 63;
  const int bid = blockIdx.x;
  const int b = (bid & 7) >> 1;                   // XCD-pair affinity
  const int t = ((bid >> 3) << 1) | (bid & 1);    // 0..255
  float cv = 1.f, sv = 0.f;
  if (lane < NQ) sincosf(0.5f * w[lane], &sv, &cv);
  uint2* g2 = reinterpret_cast<uint2*>(stp) + ((size_t)b << 19) + ((size_t)t << 11);
  float v[16];
  float4* v4 = reinterpret_cast<float4*>(v);

  // ---- S1: v={a0,a1,a11,a12}; tid=a2..a10; link (12,11) ----
  if (INIT) {
    // state after x-RYs + layer-1 links (20,19)..(13,12): 9-bit pre-image h^(h>>1)
    float cx = 1.f, sx = 0.f;
    if (lane < NQ) sincosf(0.5f * x[b * NQ + lane], &sx, &cx);
    float Qp = 1.f;
#pragma unroll
    for (int i = 0; i < 9; ++i) {                 // tid_i = g(2+i) -> q18-i
      float cq = __shfl(cx, 18 - i), sq = __shfl(sx, 18 - i);
      Qp *= ((tid >> i) & 1) ? sq : cq;
    }
    float hfac[2];
#pragma unroll
    for (int bb = 0; bb < 2; ++bb) {              // h = g12..g20 = (t<<1)|bb
      int h = (t << 1) | bb;
      int h0 = h ^ (h >> 1);
      float p = 1.f;
#pragma unroll
      for (int j = 0; j < 9; ++j) {               // h0_j = g(12+j) -> q8-j
        float cq = __shfl(cx, 8 - j), sq = __shfl(sx, 8 - j);
        p *= ((h0 >> j) & 1) ? sq : cq;
      }
      hfac[bb] = p;
    }
    float c20 = __shfl(cx, 20), s20 = __shfl(sx, 20);
    float c19 = __shfl(cx, 19), s19 = __shfl(sx, 19);
    float c9  = __shfl(cx, 9),  s9  = __shfl(sx, 9);
    float w0t[4];
#pragma unroll
    for (int i = 0; i < 4; ++i)
      w0t[i] = ((i & 1) ? s20 : c20) * ((i & 2) ? s19 : c19);   // g0,g1
#pragma unroll
    for (int r = 0; r < 16; ++r)                  // r2=g11(q9), r3=g12
      v[r] = w0t[r & 3] * ((r & 4) ? s9 : c9) * hfac[(r >> 3) & 1] * Qp;
  } else {
#pragma unroll
    for (int rr = 0; rr < 4; ++rr) ld4(g2, tid | (rr << 9), v + 4 * rr);
  }
  cnot16<3, 2>(v);                                // (12,11)
  { // WR lambda1: sl: a11,a8,a9,a10 | a0,a1 | a2..a7 | a12 ; pairs over a11(r2)
    const int bw = (((tid >> 6) & 7) << 1) | ((tid & 63) << 6);
#pragma unroll
    for (int i = 0; i < 8; ++i) {                 // i0->a0, i1->a1, i2->a12
      int r = (i & 3) | ((i >> 2) << 3);
      int sl = bw ^ ((i & 1) << 4) ^ (((i >> 1) & 1) << 5) ^ (((i >> 2) & 1) << 12);
      st2(s, sl, v[r], v[r | 4]);
    }
  }
  __syncthreads();

  // ---- S2: v={a11,a8,a9,a10}; tid=a0..a7,a12 ----
  {
    const int base = ((tid & 255) << 2) | ((tid >> 8) << 10);
#pragma unroll
    for (int rr = 0; rr < 4; ++rr) v4[rr] = s4[PH3(base ^ rr)];
  }
  cnot16<0, 3>(v); cnot16<3, 2>(v); cnot16<2, 1>(v);   // (11,10)(10,9)(9,8)
  ry16<0>(v, SHC(9)); ry16<3>(v, SHC(10)); ry16<2>(v, SHC(11));
  __syncthreads();
  { // WR lambda2: sl: a8,a5,a6,a7 | a0..a4 | a9..a12 ; pairs over a8(r1)
    const int bw = (((tid >> 5) & 7) << 1) | ((tid & 31) << 4) | ((tid >> 8) << 12);
#pragma unroll
    for (int i = 0; i < 8; ++i) {                 // i0->a9(r2), i1->a10(r3), i2->a11(r0)
      int r = ((i & 1) << 2) | ((i & 2) << 2) | ((i >> 2) & 1);
      int sl = bw ^ ((i & 1) << 9) ^ (((i >> 1) & 1) << 10) ^ (((i >> 2) & 1) << 11);
      st2(s, sl, v[r], v[r | 2]);
    }
  }
  __syncthreads();

  // ---- S3: v={a8,a5,a6,a7}; tid=a0..a4,a9..a12 ----
#pragma unroll
  for (int rr = 0; rr < 4; ++rr) v4[rr] = s4[PH3((tid << 2) ^ rr)];
  cnot16<0, 3>(v); cnot16<3, 2>(v); cnot16<2, 1>(v);   // (8,7)(7,6)(6,5)
  ry16<0>(v, SHC(12)); ry16<3>(v, SHC(13)); ry16<2>(v, SHC(14));
  __syncthreads();
  { // WR lambda3: sl: a5,a2,a3,a4 | a0,a1 | a6,a7,a8 | a9..a12 ; pairs over a5(r1)
    const int bw = (((tid >> 2) & 7) << 1) | ((tid & 3) << 4) | (((tid >> 5) & 15) << 9);
#pragma unroll
    for (int i = 0; i < 8; ++i) {                 // i0->a6(r2), i1->a7(r3), i2->a8(r0)
      int r = ((i & 1) << 2) | ((i & 2) << 2) | ((i >> 2) & 1);
      int sl = bw ^ ((i & 1) << 6) ^ (((i >> 1) & 1) << 7) ^ (((i >> 2) & 1) << 8);
      st2(s, sl, v[r], v[r | 2]);
    }
  }
  __syncthreads();

  // ---- S4: v={a5,a2,a3,a4}; tid=a0,a1,a6..a12 ----
#pragma unroll
  for (int rr = 0; rr < 4; ++rr) v4[rr] = s4[PH3((tid << 2) ^ rr)];
  cnot16<0, 3>(v); cnot16<3, 2>(v); cnot16<2, 1>(v);   // (5,4)(4,3)(3,2)
  ry16<0>(v, SHC(15)); ry16<3>(v, SHC(16)); ry16<2>(v, SHC(17));
  __syncthreads();
  { // WR lambda4: sl: a2,a8,a0,a1 | a3,a4,a5 | a6,a7 | a9..a12 ; pairs over a2(r1)
    const int bw = (((tid >> 4) & 1) << 1) | ((tid & 3) << 2) |
                   (((tid >> 2) & 3) << 7) | (((tid >> 5) & 15) << 9);
#pragma unroll
    for (int i = 0; i < 8; ++i) {                 // i0->a3(r2), i1->a4(r3), i2->a5(r0)
      int r = ((i & 1) << 2) | ((i & 2) << 2) | ((i >> 2) & 1);
      int sl = bw ^ ((i & 1) << 4) ^ (((i >> 1) & 1) << 5) ^ (((i >> 2) & 1) << 6);
      st2(s, sl, v[r], v[r | 2]);
    }
  }
  __syncthreads();

  // ---- S5: v={a2,a8,a0,a1}; tid=a3..a7,a9..a12; links (2,1)(1,0); store ----
#pragma unroll
  for (int rr = 0; rr < 4; ++rr) v4[rr] = s4[PH3((tid << 2) ^ rr)];
  cnot16<0, 3>(v); cnot16<3, 2>(v);               // (2,1)=C(a2,a1), (1,0)=C(a1,a0)
  ry16<0>(v, SHC(18)); ry16<3>(v, SHC(19));
  {
    uint4* g4o = reinterpret_cast<uint4*>(g2);
#pragma unroll
    for (int j = 0; j < 2; ++j) {                 // j = a8 (r1)
      int b1 = j << 1;
      uint4 o;
      o.x = pkh(v[b1],     v[b1 | 4]);            // granule a2=0: (a0,a1)
      o.y = pkh(v[b1 | 8], v[b1 | 12]);
      o.z = pkh(v[b1 | 1], v[b1 | 5]);            // granule a2=1
      o.w = pkh(v[b1 | 9], v[b1 | 13]);
      g4o[(tid & 31) | (j << 5) | (((tid >> 5) & 15) << 6)] = o;
    }
  }
}

// ---------------- H pass: tile {g0..g3,g12..g20} (l0..l3,l4..l12), t=g4..g11 ----
// Sweeps: HS1{l0,l1,l11,l12} -> HS2{l8..l11} -> HS3{l5..l8} -> HS4{l0,l1,l4,l5}
__global__ __launch_bounds__(512, 8) void k_H(const float* __restrict__ w,
                                              unsigned long long stp) {
  __shared__ __align__(16) float s[8192];
  float4* s4 = reinterpret_cast<float4*>(s);
  const int tid = threadIdx.x, lane = tid & 63;
  const int bid = blockIdx.x;
  const int b = (bid & 7) >> 1;
  const int t = ((bid >> 3) << 1) | (bid & 1);
  float cv = 1.f, sv = 0.f;
  if (lane < NQ) sincosf(0.5f * w[lane], &sv, &cv);
  uint2* gb = reinterpret_cast<uint2*>(stp) + ((size_t)b << 19);
  float v[16];
  float4* v4 = reinterpret_cast<float4*>(v);

  // ---- HS1: v={l0,l1,l11,l12}; tid=l2..l10; wrap + RY q20,q0,q1 + next (g20,g19) ----
#pragma unroll
  for (int rr = 0; rr < 4; ++rr) ld4(gb, GH(tid | (rr << 9)), v + 4 * rr);
  cnot16<0, 3>(v);                                // wrap C(g0,g20)
  ry16<0>(v, SHC(20)); ry16<3>(v, SHC(0)); ry16<2>(v, SHC(1));
  cnot16<3, 2>(v);                                // next C(g20,g19)
  { // WR lambda1 (x=l): pairs over l11(r2)
    const int bw = (((tid >> 6) & 7) << 1) | ((tid & 63) << 6);
#pragma unroll
    for (int i = 0; i < 8; ++i) {
      int r = (i & 3) | ((i >> 2) << 3);
      int sl = bw ^ ((i & 1) << 4) ^ (((i >> 1) & 1) << 5) ^ (((i >> 2) & 1) << 12);
      st2(s, sl, v[r], v[r | 4]);
    }
  }
  __syncthreads();

  // ---- HS2: v={l11,l8,l9,l10}; RY q2,q3,q4 + next (g19,g18)(g18,g17)(g17,g16) ----
  {
    const int base = ((tid & 255) << 2) | ((tid >> 8) << 10);
#pragma unroll
    for (int rr = 0; rr < 4; ++rr) v4[rr] = s4[PH3(base ^ rr)];
  }
  ry16<3>(v, SHC(2)); ry16<2>(v, SHC(3)); ry16<1>(v, SHC(4));
  cnot16<0, 3>(v); cnot16<3, 2>(v); cnot16<2, 1>(v);
  __syncthreads();
  { // WR lambda2 (x=l): pairs over l8(r1)
    const int bw = (((tid >> 5) & 7) << 1) | ((tid & 31) << 4) | ((tid >> 8) << 12);
#pragma unroll
    for (int i = 0; i < 8; ++i) {
      int r = ((i & 1) << 2) | ((i & 2) << 2) | ((i >> 2) & 1);
      int sl = bw ^ ((i & 1) << 9) ^ (((i >> 1) & 1) << 10) ^ (((i >> 2) & 1) << 11);
      st2(s, sl, v[r], v[r | 2]);
    }
  }
  __syncthreads();

  // ---- HS3: v={l8,l5,l6,l7}; RY q5,q6,q7 + next (g16,g15)(g15,g14)(g14,g13) ----
#pragma unroll
  for (int rr = 0; rr < 4; ++rr) v4[rr] = s4[PH3((tid << 2) ^ rr)];
  ry16<3>(v, SHC(5)); ry16<2>(v, SHC(6)); ry16<1>(v, SHC(7));
  cnot16<0, 3>(v); cnot16<3, 2>(v); cnot16<2, 1>(v);
  __syncthreads();
  { // WR lambda3H: sl: l5,l4,l0,l1 | l2,l3 | l6,l7,l8 | l9..l12 ; pairs over l5(r1)
    const int bw = (((tid >> 4) & 1) << 1) | ((tid & 15) << 2) | (((tid >> 5) & 15) << 9);
#pragma unroll
    for (int i = 0; i < 8; ++i) {                 // i0->l6(r2), i1->l7(r3), i2->l8(r0)
      int r = ((i & 1) << 2) | ((i & 2) << 2) | ((i >> 2) & 1);
      int sl = bw ^ ((i & 1) << 6) ^ (((i >> 1) & 1) << 7) ^ (((i >> 2) & 1) << 8);
      st2(s, sl, v[r], v[r | 2]);
    }
  }
  __syncthreads();

  // ---- HS4: v={l5,l4,l0,l1}; tid=l2,l3,l6..l12; RY q8 + next (g13,g12); store ----
#pragma unroll
  for (int rr = 0; rr < 4; ++rr) v4[rr] = s4[PH3((tid << 2) ^ rr)];
  ry16<1>(v, SHC(8));
  cnot16<0, 1>(v);                                // C(g13,g12) = C(l5,l4)
#pragma unroll
  for (int i = 0; i < 4; ++i) {                   // i0 = l5(r0), i1 = l4(r1)
    int r0b = i & 1, r1b = (i >> 1) & 1;
    int rb = r0b | (r1b << 1);
    int lg = (tid & 3) | (r1b << 2) | (r0b << 3) | ((tid >> 2) << 4);
    uint2 o;
    o.x = pkh(v[rb], v[rb | 4]);
    o.y = pkh(v[rb | 8], v[rb | 12]);
    gb[GH(lg)] = o;
  }
}

// ---------------- final H pass + measurement ----------------
__global__ __launch_bounds__(512, 8) void k_Hfin(const float* __restrict__ w,
                                                 unsigned long long stp,
                                                 float* __restrict__ partial) {
  __shared__ __align__(16) float s[8192];
  float4* s4 = reinterpret_cast<float4*>(s);
  const int tid = threadIdx.x, lane = tid & 63;
  const int bid = blockIdx.x;
  const int b = (bid & 7) >> 1;
  const int t = ((bid >> 3) << 1) | (bid & 1);
  float cv = 1.f, sv = 0.f;
  if (lane < NQ) sincosf(0.5f * w[lane], &sv, &cv);
  const uint2* gb = reinterpret_cast<const uint2*>(stp) + ((size_t)b << 19);
  float v[16];
  float4* v4 = reinterpret_cast<float4*>(v);

  // ---- HS1f: wrap + RY q20,q0,q1 ----
#pragma unroll
  for (int rr = 0; rr < 4; ++rr) ld4(gb, GH(tid | (rr << 9)), v + 4 * rr);
  cnot16<0, 3>(v);
  ry16<0>(v, SHC(20)); ry16<3>(v, SHC(0)); ry16<2>(v, SHC(1));
  {
    const int bw = (((tid >> 6) & 7) << 1) | ((tid & 63) << 6);
#pragma unroll
    for (int i = 0; i < 8; ++i) {
      int r = (i & 3) | ((i >> 2) << 3);
      int sl = bw ^ ((i & 1) << 4) ^ (((i >> 1) & 1) << 5) ^ (((i >> 2) & 1) << 12);
      st2(s, sl, v[r], v[r | 4]);
    }
  }
  __syncthreads();

  // ---- HS2f: RY q2,q3,q4 ----
  {
    const int base = ((tid & 255) << 2) | ((tid >> 8) << 10);
#pragma unroll
    for (int rr = 0; rr < 4; ++rr) v4[rr] = s4[PH3(base ^ rr)];
  }
  ry16<3>(v, SHC(2)); ry16<2>(v, SHC(3)); ry16<1>(v, SHC(4));
  __syncthreads();
  {
    const int bw = (((tid >> 5) & 7) << 1) | ((tid & 31) << 4) | ((tid >> 8) << 12);
#pragma unroll
    for (int i = 0; i < 8; ++i) {
      int r = ((i & 1) << 2) | ((i & 2) << 2) | ((i >> 2) & 1);
      int sl = bw ^ ((i & 1) << 9) ^ (((i >> 1) & 1) << 10) ^ (((i >> 2) & 1) << 11);
      st2(s, sl, v[r], v[r | 2]);
    }
  }
  __syncthreads();

  // ---- HS3f: RY q5,q6,q7 ----
#pragma unroll
  for (int rr = 0; rr < 4; ++rr) v4[rr] = s4[PH3((tid << 2) ^ rr)];
  ry16<3>(v, SHC(5)); ry16<2>(v, SHC(6)); ry16<1>(v, SHC(7));
  __syncthreads();
  {
    const int bw = (((tid >> 4) & 1) << 1) | ((tid & 15) << 2) | (((tid >> 5) & 15) << 9);
#pragma unroll
    for (int i = 0; i < 8; ++i) {
      int r = ((i & 1) << 2) | ((i & 2) << 2) | ((i >> 2) & 1);
      int sl = bw ^ ((i & 1) << 6) ^ (((i >> 1) & 1) << 7) ^ (((i >> 2) & 1) << 8);
      st2(s, sl, v[r], v[r | 2]);
    }
  }
  __syncthreads();

  // ---- HS4f: v={l5,l4,l0,l1}; tid=l2,l3,l6..l12; RY q8; measure ----
#pragma unroll
  for (int rr = 0; rr < 4; ++rr) v4[rr] = s4[PH3((tid << 2) ^ rr)];
  __syncthreads();   // LDS reads done; s reused for reduction
  ry16<1>(v, SHC(8));

  // reg bits: r0=l5=g13(q7), r1=l4=g12(q8), r2=l0=g0(q20), r3=l1=g1(q19)
  float S = 0, aq7 = 0, aq8 = 0, aq20 = 0, aq19 = 0;
#pragma unroll
  for (int r = 0; r < 16; ++r) {
    float p = v[r] * v[r];
    S += p;
    aq7  += (r & 1) ? -p : p;
    aq8  += (r & 2) ? -p : p;
    aq20 += (r & 4) ? -p : p;
    aq19 += (r & 8) ? -p : p;
  }
  float a21[21];
  a21[7] = aq7; a21[8] = aq8; a21[20] = aq20; a21[19] = aq19;
  a21[18] = (tid & 1)   ? -S : S;  // t0=l2=g2
  a21[17] = (tid & 2)   ? -S : S;  // t1=l3=g3
  a21[6]  = (tid & 4)   ? -S : S;  // t2=l6=g14
  a21[5]  = (tid & 8)   ? -S : S;  // t3=l7=g15
  a21[4]  = (tid & 16)  ? -S : S;  // t4=l8=g16
  a21[3]  = (tid & 32)  ? -S : S;  // t5=l9=g17
  a21[2]  = (tid & 64)  ? -S : S;  // t6=l10=g18
  a21[1]  = (tid & 128) ? -S : S;  // t7=l11=g19
  a21[0]  = (tid & 256) ? -S : S;  // t8=l12=g20
  a21[16] = (t & 1)   ? -S : S;    // g4
  a21[15] = (t & 2)   ? -S : S;
  a21[14] = (t & 4)   ? -S : S;
  a21[13] = (t & 8)   ? -S : S;
  a21[12] = (t & 16)  ? -S : S;
  a21[11] = (t & 32)  ? -S : S;
  a21[10] = (t & 64)  ? -S : S;
  a21[9]  = (t & 128) ? -S : S;    // g11

  const int wv = tid >> 6;
#pragma unroll
  for (int q = 0; q < 21; ++q) {
    float val = a21[q];
    val += __shfl_down(val, 32);
    val += __shfl_down(val, 16);
    val += __shfl_down(val, 8);
    val += __shfl_down(val, 4);
    val += __shfl_down(val, 2);
    val += __shfl_down(val, 1);
    if (lane == 0) s[q * 8 + wv] = val;
  }
  __syncthreads();
  if (tid < NQ) {
    float sum = 0.f;
#pragma unroll
    for (int k = 0; k < 8; ++k) sum += s[tid * 8 + k];
    partial[bid * NQ + tid] = sum;
  }
}

// ---------------- deterministic final reduction (1 block x 672) ----------------
__global__ void k_red(const float* __restrict__ partial, float* __restrict__ out) {
  __shared__ float red[84][8];
  const int tid = threadIdx.x;
  const int pair = tid >> 3, k8 = tid & 7;
  if (pair < 84) {
    int b = pair / NQ, q = pair % NQ;
    float sum = 0.f;
#pragma unroll
    for (int i = 0; i < 16; ++i) {
      int m = k8 * 16 + i;
      sum += partial[(((m << 3) | (2 * b + 0)) * NQ) + q];
      sum += partial[(((m << 3) | (2 * b + 1)) * NQ) + q];
    }
    red[pair][k8] = sum;
  }
  __syncthreads();
  if (tid < 84) {
    float sum = 0.f;
#pragma unroll
    for (int k = 0; k < 8; ++k) sum += red[tid][k];
    out[tid] = sum;     // tid == b*21 + q
  }
}

extern "C" void kernel_launch(void* const* d_in, const int* in_sizes, int n_in,
                              void* d_out, int out_size, void* d_ws, size_t ws_size,
                              hipStream_t stream) {
  const float* x = (const float*)d_in[0];   // (4,21) f32
  const float* w = (const float*)d_in[1];   // (3,21) f32
  float* out = (float*)d_out;               // (4,21) f32
  unsigned long long stp = (unsigned long long)d_ws;                 // 16 MB fp16 state
  const size_t st_bytes = ((size_t)4 << 21) * 2;
  float* partial = (float*)((char*)d_ws + st_bytes);                 // 1024*21 f32
  if (ws_size < st_bytes + (size_t)1024 * NQ * 4) return;

  dim3 grid(1024), blk(512);
  k_L<true> <<<grid, blk, 0, stream>>>(x, w +  0, stp);
  k_H       <<<grid, blk, 0, stream>>>(w +  0, stp);
  k_L<false><<<grid, blk, 0, stream>>>(nullptr, w + 21, stp);
  k_H       <<<grid, blk, 0, stream>>>(w + 21, stp);
  k_L<false><<<grid, blk, 0, stream>>>(nullptr, w + 42, stp);
  k_Hfin    <<<grid, blk, 0, stream>>>(w + 42, stp, partial);
  k_red     <<<1, dim3(672), 0, stream>>>(partial, out);
}

// Round 10
// 104.553 us; speedup vs baseline: 1.2547x; 1.2547x over previous
//
#include <hip/hip_runtime.h>
#include <hip/hip_fp16.h>

// 21-qubit batched (B=4) state-vector simulator, 6 split passes (R8 structure,
// 95.2us verified). R10: k_red folded into k_Hfin via release-counter +
// relaxed-spin reducer blocks (512 blocks = exact co-residency at 2/CU).
// Conflict-free LDS layouts (writer∩reader window intersections, paired
// b64/quad b128 stores), XCD batch affinity, fp16 global state, f32 LDS.
// Qubit q <-> g-bit (20-q).

#define NQ 21
#define SHC(q) __shfl(cv, (q)), __shfl(sv, (q))

__device__ __forceinline__ int PH2B(int blk) {        // granule swizzle
  return blk ^ ((blk >> 3) & 7) ^ ((blk >> 6) & 7);
}

template<int Q>
__device__ __forceinline__ void ry32(float* v, float c, float s) {
#pragma unroll
  for (int k = 0; k < 16; ++k) {
    int l0 = ((k >> Q) << (Q + 1)) | (k & ((1 << Q) - 1));
    int l1 = l0 | (1 << Q);
    float a0 = v[l0], a1 = v[l1];
    v[l0] = c * a0 - s * a1;
    v[l1] = s * a0 + c * a1;
  }
}

template<int C, int T>
__device__ __forceinline__ void cnot32(float* v) {
  constexpr int lo = (C < T) ? C : T;
  constexpr int hi = (C < T) ? T : C;
#pragma unroll
  for (int k = 0; k < 8; ++k) {
    int i1 = ((k >> lo) << (lo + 1)) | (k & ((1 << lo) - 1));
    int i2 = ((i1 >> hi) << (hi + 1)) | (i1 & ((1 << hi) - 1));
    int a = i2 | (1 << C);
    int b = a | (1 << T);
    float tmp = v[a]; v[a] = v[b]; v[b] = tmp;
  }
}

__device__ __forceinline__ void ld4(const uint2* __restrict__ g, int idx, float* dst) {
  uint2 r = g[idx];
  __half2 h0 = *reinterpret_cast<__half2*>(&r.x);
  __half2 h1 = *reinterpret_cast<__half2*>(&r.y);
  float2 f0 = __half22float2(h0), f1 = __half22float2(h1);
  dst[0] = f0.x; dst[1] = f0.y; dst[2] = f1.x; dst[3] = f1.y;
}
__device__ __forceinline__ unsigned pkh(float a, float b) {
  __half2 h = __floats2half2_rn(a, b);
  return *reinterpret_cast<unsigned*>(&h);
}

#define A1 (tid | (rr << 9))
#define GH(l4) (((l4) & 0xF) | (t << 4) | (((l4) >> 4) << 11))

// sigma2-style write (S1/HS1): pairs over v-bit2; slot: s0=w2bit, s1=tid5,
// s2..6=tid0..4, s7,8=r0,r1, s9..11=tid6..8, s12,13=r3,r4.
#define WR_SIGMA2(s, v)                                                        \
  {                                                                            \
    const int pbs = (((tid >> 5) & 1) << 1) | ((tid & 31) << 2) |              \
                    (((tid >> 6) & 7) << 9);                                   \
    _Pragma("unroll") for (int i = 0; i < 16; ++i) {                           \
      int r = (i & 3) | ((i >> 2) << 3);                                       \
      int sl = pbs ^ (((i & 3) << 7) | ((i >> 2) << 12));                      \
      int a = (PH2B(sl >> 2) << 2) | (sl & 3);                                 \
      float2 o; o.x = (v)[r]; o.y = (v)[r | 4];                                \
      *reinterpret_cast<float2*>((s) + a) = o;                                 \
    }                                                                          \
  }

// sigma2-style read (S2/HS2): v0=w-bit at s0, v1=bit at s1, v2..4=rr (blk7..9)
#define RD_SIGMA2(s4, v4)                                                      \
  {                                                                            \
    const int pbb = (tid & 31) | (((tid >> 5) & 3) << 5) |                     \
                    (((tid >> 7) & 3) << 10);                                  \
    _Pragma("unroll") for (int rr = 0; rr < 8; ++rr)                          \
      (v4)[rr] = (s4)[PH2B(pbb ^ (rr << 7))];                                  \
  }

// ---------------- L pass: tile = bits 0..13, t = bits 14..20 ----------------
template<bool INIT>
__global__ __launch_bounds__(512, 4) void k_L(const float* __restrict__ x,
                                              const float* __restrict__ w,
                                              unsigned long long stp,
                                              unsigned* __restrict__ cnt) {
  __shared__ __align__(16) float s[16384];
  float4* s4 = reinterpret_cast<float4*>(s);
  const int tid = threadIdx.x, lane = tid & 63;
  const int bid = blockIdx.x;
  const int b = (bid & 7) >> 1;                       // XCD-pair affinity
  const int t = ((bid >> 3) << 1) | (bid & 1);
  if (INIT && bid == 0 && tid == 0) *cnt = 0u;        // reset reducer counter
  float cv = 1.f, sv = 0.f;
  if (lane < NQ) sincosf(0.5f * w[lane], &sv, &cv);
  uint2* g2 = reinterpret_cast<uint2*>(stp) + ((size_t)b << 19) + ((size_t)t << 12);
  float v[32];
  float4* v4 = reinterpret_cast<float4*>(v);

  // ---- S1: v = {amp0,amp1 | rr=amp11,12,13}: C(13,12),(12,11); RY q7,q8 ----
  if (INIT) {
    float cx = 1.f, sx = 0.f;
    if (lane < NQ) sincosf(0.5f * x[b * NQ + lane], &sx, &cx);
    float Qp = 1.f;
#pragma unroll
    for (int i = 0; i < 9; ++i) {            // tid bit i -> g(2+i) -> qubit 18-i
      float cq = __shfl(cx, 18 - i), sq = __shfl(sx, 18 - i);
      Qp *= ((tid >> i) & 1) ? sq : cq;
    }
    float hfac[2];
#pragma unroll
    for (int bb = 0; bb < 2; ++bb) {         // g13 = bb, h = g[13..20]
      int h = (t << 1) | bb;
      int h0 = h ^ (h >> 1);                 // pre-image of high chain
      float p = 1.f;
#pragma unroll
      for (int j = 0; j < 8; ++j) {
        float cq = __shfl(cx, 7 - j), sq = __shfl(sx, 7 - j);
        p *= ((h0 >> j) & 1) ? sq : cq;
      }
      hfac[bb] = p;
    }
    float c20 = __shfl(cx, 20), s20 = __shfl(sx, 20);
    float c19 = __shfl(cx, 19), s19 = __shfl(sx, 19);
    float c9  = __shfl(cx, 9),  s9  = __shfl(sx, 9);
    float c8  = __shfl(cx, 8),  s8  = __shfl(sx, 8);
    float w0t[4], w1t[4];
#pragma unroll
    for (int i = 0; i < 4; ++i) {
      w0t[i] = ((i & 1) ? s20 : c20) * ((i & 2) ? s19 : c19);  // amps 0,1
      w1t[i] = ((i & 1) ? s9  : c9 ) * ((i & 2) ? s8  : c8 );  // amps 11,12
    }
#pragma unroll
    for (int r = 0; r < 32; ++r)
      v[r] = hfac[(r >> 4) & 1] * w1t[(r >> 2) & 3] * w0t[r & 3] * Qp;
  } else {
#pragma unroll
    for (int rr = 0; rr < 8; ++rr) ld4(g2, A1, v + 4 * rr);
  }
  cnot32<4, 3>(v); cnot32<3, 2>(v);
  ry32<4>(v, SHC(7)); ry32<3>(v, SHC(8));
  WR_SIGMA2(s, v);                           // s0=amp11
  __syncthreads();

  // ---- S2: v = {amp11,amp7 | rr=amp8,9,10}: C(11,10),(10,9),(9,8),(8,7) ----
  RD_SIGMA2(s4, v4);
  cnot32<0, 4>(v); cnot32<4, 3>(v); cnot32<3, 2>(v); cnot32<2, 1>(v);
  ry32<0>(v, SHC(9)); ry32<4>(v, SHC(10)); ry32<3>(v, SHC(11)); ry32<2>(v, SHC(12));
  __syncthreads();
  {
    // sigma3: s0=amp7(pair), s1=amp3, s2=amp4, s3=amp5, s4=amp6, s5=amp2,
    // s6=amp1, s7=amp0, s8..10=amp8..10, s11=amp11, s12,13=amp12,13
    const int pbs = (tid & 0x1E) | ((tid & 1) << 5) | (tid & 0x40) |
                    (((tid >> 5) & 1) << 7) | ((tid >> 7) << 12);
#pragma unroll
    for (int i = 0; i < 16; ++i) {
      int r = (i & 1) | ((i >> 1) << 2);
      int sl = pbs ^ ((((i >> 1) & 7) << 8) | ((i & 1) << 11));
      int a = (PH2B(sl >> 2) << 2) | (sl & 3);
      float2 o; o.x = v[r]; o.y = v[r | 2];
      *reinterpret_cast<float2*>(s + a) = o;
    }
  }
  __syncthreads();

  // ---- S3: v = {amp7,amp3 | rr=amp4,5,6}: C(7,6),(6,5),(5,4),(4,3) ----
  {
    const int pbb = ((tid & 7) << 3) | (((tid >> 3) & 7) << 6) | (((tid >> 6) & 7) << 9);
#pragma unroll
    for (int rr = 0; rr < 8; ++rr) v4[rr] = s4[PH2B(pbb | rr)];
  }
  cnot32<0, 4>(v); cnot32<4, 3>(v); cnot32<3, 2>(v); cnot32<2, 1>(v);
  ry32<0>(v, SHC(13)); ry32<4>(v, SHC(14)); ry32<3>(v, SHC(15)); ry32<2>(v, SHC(16));
  __syncthreads();
  {
    // identity'': s0=amp3, s1=amp4 (quads), s2=amp0, s3=amp1, s4=amp2,
    // s5=amp5, s6=amp6, s7=amp7, s8..13=amp8..13
    const int pbs = (((tid >> 2) & 1) << 2) | (((tid >> 1) & 1) << 3) |
                    ((tid & 1) << 4) | (((tid >> 3) & 7) << 8) |
                    (((tid >> 6) & 7) << 11);
#pragma unroll
    for (int i = 0; i < 8; ++i) {
      int r = (i & 1) | ((i >> 1) << 3);
      int sl = pbs ^ ((((i >> 1) & 1) << 5) | (((i >> 2) & 1) << 6) | ((i & 1) << 7));
      int a = PH2B(sl >> 2) << 2;
      float4 o; o.x = v[r]; o.y = v[r | 2]; o.z = v[r | 4]; o.w = v[r | 6];
      *reinterpret_cast<float4*>(s + a) = o;
    }
  }
  __syncthreads();

  // ---- S4: v = {amp3,amp4 | rr=amp0,1,2}: C(3,2),(2,1),(1,0); RY q17..q19 ----
  {
    const int pbb = tid << 3;
#pragma unroll
    for (int rr = 0; rr < 8; ++rr) v4[rr] = s4[PH2B(pbb | rr)];
  }
  cnot32<0, 4>(v); cnot32<4, 3>(v); cnot32<3, 2>(v);
  ry32<0>(v, SHC(17)); ry32<4>(v, SHC(18)); ry32<3>(v, SHC(19));
  {
    uint4* g4o = reinterpret_cast<uint4*>(g2);
#pragma unroll
    for (int i = 0; i < 4; ++i) {            // i = {a3, a4}
      int c = (i & 1) | ((i >> 1) << 1);
      uint4 o;
      o.x = pkh(v[c], v[c + 4]);   o.y = pkh(v[c + 8], v[c + 12]);
      o.z = pkh(v[c + 16], v[c + 20]); o.w = pkh(v[c + 24], v[c + 28]);
      g4o[(i & 1) | ((i >> 1) << 1) | (tid << 2)] = o;
    }
  }
}

// ---------------- H pass: tile = {g0..g5, g13..g20} (l0..l5, l6..l13) ----------------
__global__ __launch_bounds__(512, 4) void k_H(const float* __restrict__ w,
                                              unsigned long long stp) {
  __shared__ __align__(16) float s[16384];
  float4* s4 = reinterpret_cast<float4*>(s);
  const int tid = threadIdx.x, lane = tid & 63;
  const int bid = blockIdx.x;
  const int b = (bid & 7) >> 1;
  const int t = ((bid >> 3) << 1) | (bid & 1);
  float cv = 1.f, sv = 0.f;
  if (lane < NQ) sincosf(0.5f * w[lane], &sv, &cv);
  uint2* gb = reinterpret_cast<uint2*>(stp) + ((size_t)b << 19);
  float v[32];
  float4* v4 = reinterpret_cast<float4*>(v);

  // ---- HS1: v = {l0,l1 | rr=l11,l12,l13}: wrap C(g0,g20); RY q20,q0,q1,q2;
  //      next-layer chain C(l13,l12),(l12,l11) ----
#pragma unroll
  for (int rr = 0; rr < 8; ++rr) ld4(gb, GH(A1), v + 4 * rr);
  cnot32<0, 4>(v);
  ry32<0>(v, SHC(20)); ry32<4>(v, SHC(0)); ry32<3>(v, SHC(1)); ry32<2>(v, SHC(2));
  cnot32<4, 3>(v); cnot32<3, 2>(v);
  WR_SIGMA2(s, v);                           // s0=l11
  __syncthreads();

  // ---- HS2: v = {l11,l7 | rr=l8,l9,l10}: RY q3..q6; chain C(l11,l10)..(l8,l7) ----
  RD_SIGMA2(s4, v4);
  ry32<4>(v, SHC(3)); ry32<3>(v, SHC(4)); ry32<2>(v, SHC(5)); ry32<1>(v, SHC(6));
  cnot32<0, 4>(v); cnot32<4, 3>(v); cnot32<3, 2>(v); cnot32<2, 1>(v);
  __syncthreads();
  {
    // sigma3H: s0=l7(pair), s1=l5, s2=l0, s3=l1, s4=l6, s5=l2, s6=l3, s7=l4,
    // s8..10=l8..10, s11=l11, s12,13=l12,13
    const int pbs = (((tid >> 3) & 1) << 1) | (((tid >> 5) & 1) << 2) |
                    (((tid >> 6) & 1) << 3) | (tid & 16) | ((tid & 1) << 5) |
                    (((tid >> 1) & 1) << 6) | (((tid >> 2) & 1) << 7) |
                    ((tid >> 7) << 12);
#pragma unroll
    for (int i = 0; i < 16; ++i) {
      int r = (i & 1) | ((i >> 1) << 2);
      int sl = pbs ^ ((((i >> 1) & 7) << 8) | ((i & 1) << 11));
      int a = (PH2B(sl >> 2) << 2) | (sl & 3);
      float2 o; o.x = v[r]; o.y = v[r | 2];
      *reinterpret_cast<float2*>(s + a) = o;
    }
  }
  __syncthreads();

  // ---- HS3: v = {l7,l5 | rr=l0,l1,l6}: chain C(l7,l6); store ----
  {
    const int pbb = ((tid & 7) << 3) | (((tid >> 3) & 7) << 6) | (((tid >> 6) & 7) << 9);
#pragma unroll
    for (int rr = 0; rr < 8; ++rr) v4[rr] = s4[PH2B(pbb | rr)];
  }
  cnot32<0, 4>(v);
#pragma unroll
  for (int i = 0; i < 8; ++i) {              // i = {r0(l7), r1(l5), r4(l6)}
    int r0 = i & 1, r1 = (i >> 1) & 1, rh = (i >> 2) & 1;
    int c = r0 | (r1 << 1) | (rh << 4);
    int gidx = (tid & 7) | (r1 << 3) | (t << 4) |
               ((rh | (r0 << 1) | (((tid >> 3) & 0x3F) << 2)) << 11);
    uint2 o; o.x = pkh(v[c], v[c + 4]); o.y = pkh(v[c + 8], v[c + 12]);
    gb[gidx] = o;
  }
}

// ---------------- final H pass + measurement + folded reduction ----------------
__global__ __launch_bounds__(512, 4) void k_Hfin(const float* __restrict__ w,
                                                 unsigned long long stp,
                                                 float* __restrict__ partial,
                                                 unsigned* __restrict__ cnt,
                                                 float* __restrict__ out) {
  __shared__ __align__(16) float s[16384];
  float4* s4 = reinterpret_cast<float4*>(s);
  const int tid = threadIdx.x, lane = tid & 63;
  const int bid = blockIdx.x;
  const int b = (bid & 7) >> 1;
  const int t = ((bid >> 3) << 1) | (bid & 1);
  float cv = 1.f, sv = 0.f;
  if (lane < NQ) sincosf(0.5f * w[lane], &sv, &cv);
  const uint2* gb = reinterpret_cast<const uint2*>(stp) + ((size_t)b << 19);
  float v[32];
  float4* v4 = reinterpret_cast<float4*>(v);

  // ---- HS1f: wrap; RY q20,q0,q1,q2 ----
#pragma unroll
  for (int rr = 0; rr < 8; ++rr) ld4(gb, GH(A1), v + 4 * rr);
  cnot32<0, 4>(v);
  ry32<0>(v, SHC(20)); ry32<4>(v, SHC(0)); ry32<3>(v, SHC(1)); ry32<2>(v, SHC(2));
  WR_SIGMA2(s, v);
  __syncthreads();

  // ---- HS2f: v = {l11,l7 | rr=l8,l9,l10}: RY q3..q6; measure ----
  RD_SIGMA2(s4, v4);
  __syncthreads();   // all LDS reads done; s reused for reduction below
  ry32<4>(v, SHC(3)); ry32<3>(v, SHC(4)); ry32<2>(v, SHC(5)); ry32<1>(v, SHC(6));

  // v bits: 0=l11(q2), 1=l7(q6), 2=l8(q5), 3=l9(q4), 4=l10(q3)
  float S = 0, aq2 = 0, aq6 = 0, aq5 = 0, aq4 = 0, aq3 = 0;
#pragma unroll
  for (int r = 0; r < 32; ++r) {
    float p = v[r] * v[r];
    S += p;
    aq2 += (r & 1)  ? -p : p;
    aq6 += (r & 2)  ? -p : p;
    aq5 += (r & 4)  ? -p : p;
    aq4 += (r & 8)  ? -p : p;
    aq3 += (r & 16) ? -p : p;
  }
  float a21[21];
  a21[2] = aq2; a21[6] = aq6; a21[5] = aq5; a21[4] = aq4; a21[3] = aq3;
  a21[18] = (tid & 1)   ? -S : S;
  a21[17] = (tid & 2)   ? -S : S;
  a21[16] = (tid & 4)   ? -S : S;
  a21[15] = (tid & 8)   ? -S : S;
  a21[7]  = (tid & 16)  ? -S : S;
  a21[20] = (tid & 32)  ? -S : S;
  a21[19] = (tid & 64)  ? -S : S;
  a21[1]  = (tid & 128) ? -S : S;
  a21[0]  = (tid & 256) ? -S : S;
  a21[14] = (t & 1)  ? -S : S;     // t bits = g6..g12 -> q14..q8
  a21[13] = (t & 2)  ? -S : S;
  a21[12] = (t & 4)  ? -S : S;
  a21[11] = (t & 8)  ? -S : S;
  a21[10] = (t & 16) ? -S : S;
  a21[9]  = (t & 32) ? -S : S;
  a21[8]  = (t & 64) ? -S : S;

  const int wv = tid >> 6;
#pragma unroll
  for (int q = 0; q < 21; ++q) {
    float val = a21[q];
    val += __shfl_down(val, 32);
    val += __shfl_down(val, 16);
    val += __shfl_down(val, 8);
    val += __shfl_down(val, 4);
    val += __shfl_down(val, 2);
    val += __shfl_down(val, 1);
    if (lane == 0) s[q * 8 + wv] = val;
  }
  __syncthreads();
  if (tid < NQ) {
    float sum = 0.f;
#pragma unroll
    for (int k = 0; k < 8; ++k) sum += s[tid * 8 + k];
    partial[((b << 7) | t) * NQ + tid] = sum;
  }
  __syncthreads();                 // all partial stores issued before signal
  if (tid == 0) {
    __threadfence();               // release: partials visible before count
    __hip_atomic_fetch_add(cnt, 1u, __ATOMIC_RELEASE, __HIP_MEMORY_SCOPE_AGENT);
  }

  // ---- folded reduction: 4 reducer blocks (t == 0), one per batch ----
  if (bid < 8 && (bid & 1) == 0) {
    if (tid == 0) {
      while (__hip_atomic_load(cnt, __ATOMIC_RELAXED, __HIP_MEMORY_SCOPE_AGENT) < 512u)
        __builtin_amdgcn_s_sleep(16);
      __threadfence();             // acquire: see all partials
    }
    __syncthreads();
    float* red = s + 4096;
    if (tid < 168) {
      int q = tid >> 3, k8 = tid & 7;
      float sum = 0.f;
#pragma unroll
      for (int i = 0; i < 16; ++i) {
        int m = k8 * 16 + i;
        sum += partial[((b << 7) | m) * NQ + q];
      }
      red[tid] = sum;
    }
    __syncthreads();
    if (tid < NQ) {
      float sum = 0.f;
#pragma unroll
      for (int k = 0; k < 8; ++k) sum += red[tid * 8 + k];
      out[b * NQ + tid] = sum;
    }
  }
}

extern "C" void kernel_launch(void* const* d_in, const int* in_sizes, int n_in,
                              void* d_out, int out_size, void* d_ws, size_t ws_size,
                              hipStream_t stream) {
  const float* x = (const float*)d_in[0];   // (4,21) f32
  const float* w = (const float*)d_in[1];   // (3,21) f32
  float* out = (float*)d_out;               // (4,21) f32
  unsigned long long stp = (unsigned long long)d_ws;            // 16 MB fp16 state
  const size_t st_bytes = ((size_t)4 << 21) * 2;
  float* partial = (float*)((char*)d_ws + st_bytes);            // 512*21 f32
  unsigned* cnt = (unsigned*)((char*)d_ws + st_bytes + 512 * NQ * 4);
  if (ws_size < st_bytes + 512 * NQ * 4 + 64) return;

  dim3 grid(512), blk(512);
  k_L<true> <<<grid, blk, 0, stream>>>(x, w +  0, stp, cnt);
  k_H       <<<grid, blk, 0, stream>>>(w +  0, stp);
  k_L<false><<<grid, blk, 0, stream>>>(nullptr, w + 21, stp, cnt);
  k_H       <<<grid, blk, 0, stream>>>(w + 21, stp);
  k_L<false><<<grid, blk, 0, stream>>>(nullptr, w + 42, stp, cnt);
  k_Hfin    <<<grid, blk, 0, stream>>>(w + 42, stp, partial, cnt, out);
}

// Round 11
// 97.442 us; speedup vs baseline: 1.3462x; 1.0730x over previous
//
#include <hip/hip_runtime.h>
#include <hip/hip_fp16.h>

// 21-qubit batched (B=4) state-vector simulator, 6 split passes + k_red (R8
// structure, 95.2us verified). R11: LDS tile stored as fp16 (32KB/block,
// compute stays f32) — same slot algebra, half the LDS bytes. Pair writes =
// b32 (cvt_pkrtz), quad writes/granule reads = b64. Conflict maps rank-checked
// (writes 2 lanes/bank = free; b64 reads uniform). fp16 global state, XCD
// batch affinity. Qubit q <-> g-bit (20-q).

#define NQ 21
#define SHC(q) __shfl(cv, (q)), __shfl(sv, (q))

__device__ __forceinline__ int PH2B(int blk) {        // granule swizzle
  return blk ^ ((blk >> 3) & 7) ^ ((blk >> 6) & 7);
}

template<int Q>
__device__ __forceinline__ void ry32(float* v, float c, float s) {
#pragma unroll
  for (int k = 0; k < 16; ++k) {
    int l0 = ((k >> Q) << (Q + 1)) | (k & ((1 << Q) - 1));
    int l1 = l0 | (1 << Q);
    float a0 = v[l0], a1 = v[l1];
    v[l0] = c * a0 - s * a1;
    v[l1] = s * a0 + c * a1;
  }
}

template<int C, int T>
__device__ __forceinline__ void cnot32(float* v) {
  constexpr int lo = (C < T) ? C : T;
  constexpr int hi = (C < T) ? T : C;
#pragma unroll
  for (int k = 0; k < 8; ++k) {
    int i1 = ((k >> lo) << (lo + 1)) | (k & ((1 << lo) - 1));
    int i2 = ((i1 >> hi) << (hi + 1)) | (i1 & ((1 << hi) - 1));
    int a = i2 | (1 << C);
    int b = a | (1 << T);
    float tmp = v[a]; v[a] = v[b]; v[b] = tmp;
  }
}

// fp16 helpers: 4 amps (8B) <-> 4 f32 regs ; 2 amps <-> 1 uint
__device__ __forceinline__ void uh4(uint2 u, float* d) {
  __half2 h0 = *reinterpret_cast<__half2*>(&u.x);
  __half2 h1 = *reinterpret_cast<__half2*>(&u.y);
  float2 f0 = __half22float2(h0), f1 = __half22float2(h1);
  d[0] = f0.x; d[1] = f0.y; d[2] = f1.x; d[3] = f1.y;
}
__device__ __forceinline__ void ld4(const uint2* __restrict__ g, int idx, float* dst) {
  uh4(g[idx], dst);
}
__device__ __forceinline__ unsigned pkh(float a, float b) {
  __half2 h = __floats2half2_rn(a, b);
  return *reinterpret_cast<unsigned*>(&h);
}

#define A1 (tid | (rr << 9))
#define GH(l4) (((l4) & 0xF) | (t << 4) | (((l4) >> 4) << 11))

// sigma2-style write (S1/HS1): pairs over v-bit2; slot: s0=w2bit, s1=tid5,
// s2..6=tid0..4, s7,8=r0,r1, s9..11=tid6..8, s12,13=r3,r4.  (fp16: b32 writes)
#define WR_SIGMA2(hs, v)                                                       \
  {                                                                            \
    const int pbs = (((tid >> 5) & 1) << 1) | ((tid & 31) << 2) |              \
                    (((tid >> 6) & 7) << 9);                                   \
    _Pragma("unroll") for (int i = 0; i < 16; ++i) {                           \
      int r = (i & 3) | ((i >> 2) << 3);                                       \
      int sl = pbs ^ (((i & 3) << 7) | ((i >> 2) << 12));                      \
      int a = (PH2B(sl >> 2) << 2) | (sl & 3);                                 \
      (hs)[a >> 1] = pkh((v)[r], (v)[r | 4]);                                  \
    }                                                                          \
  }

// sigma2-style read (S2/HS2): granule (4 amps) = uint2 b64 read + unpack
#define RD_SIGMA2(hs2, v)                                                      \
  {                                                                            \
    const int pbb = (tid & 31) | (((tid >> 5) & 3) << 5) |                     \
                    (((tid >> 7) & 3) << 10);                                  \
    _Pragma("unroll") for (int rr = 0; rr < 8; ++rr)                           \
      uh4((hs2)[PH2B(pbb ^ (rr << 7))], (v) + 4 * rr);                         \
  }

// ---------------- L pass: tile = bits 0..13, t = bits 14..20 ----------------
template<bool INIT>
__global__ __launch_bounds__(512, 4) void k_L(const float* __restrict__ x,
                                              const float* __restrict__ w,
                                              unsigned long long stp) {
  __shared__ __align__(16) unsigned hs[8192];         // 2^14 amps fp16 = 32 KB
  uint2* hs2 = reinterpret_cast<uint2*>(hs);
  const int tid = threadIdx.x, lane = tid & 63;
  const int bid = blockIdx.x;
  const int b = (bid & 7) >> 1;                       // XCD-pair affinity
  const int t = ((bid >> 3) << 1) | (bid & 1);
  float cv = 1.f, sv = 0.f;
  if (lane < NQ) sincosf(0.5f * w[lane], &sv, &cv);
  uint2* g2 = reinterpret_cast<uint2*>(stp) + ((size_t)b << 19) + ((size_t)t << 12);
  float v[32];

  // ---- S1: v = {amp0,amp1 | rr=amp11,12,13}: C(13,12),(12,11); RY q7,q8 ----
  if (INIT) {
    float cx = 1.f, sx = 0.f;
    if (lane < NQ) sincosf(0.5f * x[b * NQ + lane], &sx, &cx);
    float Qp = 1.f;
#pragma unroll
    for (int i = 0; i < 9; ++i) {            // tid bit i -> g(2+i) -> qubit 18-i
      float cq = __shfl(cx, 18 - i), sq = __shfl(sx, 18 - i);
      Qp *= ((tid >> i) & 1) ? sq : cq;
    }
    float hfac[2];
#pragma unroll
    for (int bb = 0; bb < 2; ++bb) {         // g13 = bb, h = g[13..20]
      int h = (t << 1) | bb;
      int h0 = h ^ (h >> 1);                 // pre-image of high chain
      float p = 1.f;
#pragma unroll
      for (int j = 0; j < 8; ++j) {
        float cq = __shfl(cx, 7 - j), sq = __shfl(sx, 7 - j);
        p *= ((h0 >> j) & 1) ? sq : cq;
      }
      hfac[bb] = p;
    }
    float c20 = __shfl(cx, 20), s20 = __shfl(sx, 20);
    float c19 = __shfl(cx, 19), s19 = __shfl(sx, 19);
    float c9  = __shfl(cx, 9),  s9  = __shfl(sx, 9);
    float c8  = __shfl(cx, 8),  s8  = __shfl(sx, 8);
    float w0t[4], w1t[4];
#pragma unroll
    for (int i = 0; i < 4; ++i) {
      w0t[i] = ((i & 1) ? s20 : c20) * ((i & 2) ? s19 : c19);  // amps 0,1
      w1t[i] = ((i & 1) ? s9  : c9 ) * ((i & 2) ? s8  : c8 );  // amps 11,12
    }
#pragma unroll
    for (int r = 0; r < 32; ++r)
      v[r] = hfac[(r >> 4) & 1] * w1t[(r >> 2) & 3] * w0t[r & 3] * Qp;
  } else {
#pragma unroll
    for (int rr = 0; rr < 8; ++rr) ld4(g2, A1, v + 4 * rr);
  }
  cnot32<4, 3>(v); cnot32<3, 2>(v);
  ry32<4>(v, SHC(7)); ry32<3>(v, SHC(8));
  WR_SIGMA2(hs, v);                          // s0=amp11
  __syncthreads();

  // ---- S2: v = {amp11,amp7 | rr=amp8,9,10}: C(11,10),(10,9),(9,8),(8,7) ----
  RD_SIGMA2(hs2, v);
  cnot32<0, 4>(v); cnot32<4, 3>(v); cnot32<3, 2>(v); cnot32<2, 1>(v);
  ry32<0>(v, SHC(9)); ry32<4>(v, SHC(10)); ry32<3>(v, SHC(11)); ry32<2>(v, SHC(12));
  __syncthreads();
  {
    // sigma3: s0=amp7(pair), s1=amp3, s2=amp4, s3=amp5, s4=amp6, s5=amp2,
    // s6=amp1, s7=amp0, s8..10=amp8..10, s11=amp11, s12,13=amp12,13
    const int pbs = (tid & 0x1E) | ((tid & 1) << 5) | (tid & 0x40) |
                    (((tid >> 5) & 1) << 7) | ((tid >> 7) << 12);
#pragma unroll
    for (int i = 0; i < 16; ++i) {
      int r = (i & 1) | ((i >> 1) << 2);
      int sl = pbs ^ ((((i >> 1) & 7) << 8) | ((i & 1) << 11));
      int a = (PH2B(sl >> 2) << 2) | (sl & 3);
      hs[a >> 1] = pkh(v[r], v[r | 2]);
    }
  }
  __syncthreads();

  // ---- S3: v = {amp7,amp3 | rr=amp4,5,6}: C(7,6),(6,5),(5,4),(4,3) ----
  {
    const int pbb = ((tid & 7) << 3) | (((tid >> 3) & 7) << 6) | (((tid >> 6) & 7) << 9);
#pragma unroll
    for (int rr = 0; rr < 8; ++rr) uh4(hs2[PH2B(pbb | rr)], v + 4 * rr);
  }
  cnot32<0, 4>(v); cnot32<4, 3>(v); cnot32<3, 2>(v); cnot32<2, 1>(v);
  ry32<0>(v, SHC(13)); ry32<4>(v, SHC(14)); ry32<3>(v, SHC(15)); ry32<2>(v, SHC(16));
  __syncthreads();
  {
    // identity'': s0=amp3, s1=amp4 (quads), s2=amp0, s3=amp1, s4=amp2,
    // s5=amp5, s6=amp6, s7=amp7, s8..13=amp8..13  (b64 quad writes)
    const int pbs = (((tid >> 2) & 1) << 2) | (((tid >> 1) & 1) << 3) |
                    ((tid & 1) << 4) | (((tid >> 3) & 7) << 8) |
                    (((tid >> 6) & 7) << 11);
#pragma unroll
    for (int i = 0; i < 8; ++i) {
      int r = (i & 1) | ((i >> 1) << 3);
      int sl = pbs ^ ((((i >> 1) & 1) << 5) | (((i >> 2) & 1) << 6) | ((i & 1) << 7));
      uint2 o; o.x = pkh(v[r], v[r | 2]); o.y = pkh(v[r | 4], v[r | 6]);
      hs2[PH2B(sl >> 2)] = o;
    }
  }
  __syncthreads();

  // ---- S4: v = {amp3,amp4 | rr=amp0,1,2}: C(3,2),(2,1),(1,0); RY q17..q19 ----
  {
    const int pbb = tid << 3;
#pragma unroll
    for (int rr = 0; rr < 8; ++rr) uh4(hs2[PH2B(pbb | rr)], v + 4 * rr);
  }
  cnot32<0, 4>(v); cnot32<4, 3>(v); cnot32<3, 2>(v);
  ry32<0>(v, SHC(17)); ry32<4>(v, SHC(18)); ry32<3>(v, SHC(19));
  {
    uint4* g4o = reinterpret_cast<uint4*>(g2);
#pragma unroll
    for (int i = 0; i < 4; ++i) {            // i = {a3, a4}
      int c = (i & 1) | ((i >> 1) << 1);
      uint4 o;
      o.x = pkh(v[c], v[c + 4]);   o.y = pkh(v[c + 8], v[c + 12]);
      o.z = pkh(v[c + 16], v[c + 20]); o.w = pkh(v[c + 24], v[c + 28]);
      g4o[(i & 1) | ((i >> 1) << 1) | (tid << 2)] = o;
    }
  }
}

// ---------------- H pass: tile = {g0..g5, g13..g20} (l0..l5, l6..l13) ----------------
__global__ __launch_bounds__(512, 4) void k_H(const float* __restrict__ w,
                                              unsigned long long stp) {
  __shared__ __align__(16) unsigned hs[8192];
  uint2* hs2 = reinterpret_cast<uint2*>(hs);
  const int tid = threadIdx.x, lane = tid & 63;
  const int bid = blockIdx.x;
  const int b = (bid & 7) >> 1;
  const int t = ((bid >> 3) << 1) | (bid & 1);
  float cv = 1.f, sv = 0.f;
  if (lane < NQ) sincosf(0.5f * w[lane], &sv, &cv);
  uint2* gb = reinterpret_cast<uint2*>(stp) + ((size_t)b << 19);
  float v[32];

  // ---- HS1: v = {l0,l1 | rr=l11,l12,l13}: wrap C(g0,g20); RY q20,q0,q1,q2;
  //      next-layer chain C(l13,l12),(l12,l11) ----
#pragma unroll
  for (int rr = 0; rr < 8; ++rr) ld4(gb, GH(A1), v + 4 * rr);
  cnot32<0, 4>(v);
  ry32<0>(v, SHC(20)); ry32<4>(v, SHC(0)); ry32<3>(v, SHC(1)); ry32<2>(v, SHC(2));
  cnot32<4, 3>(v); cnot32<3, 2>(v);
  WR_SIGMA2(hs, v);                          // s0=l11
  __syncthreads();

  // ---- HS2: v = {l11,l7 | rr=l8,l9,l10}: RY q3..q6; chain C(l11,l10)..(l8,l7) ----
  RD_SIGMA2(hs2, v);
  ry32<4>(v, SHC(3)); ry32<3>(v, SHC(4)); ry32<2>(v, SHC(5)); ry32<1>(v, SHC(6));
  cnot32<0, 4>(v); cnot32<4, 3>(v); cnot32<3, 2>(v); cnot32<2, 1>(v);
  __syncthreads();
  {
    // sigma3H: s0=l7(pair), s1=l5, s2=l0, s3=l1, s4=l6, s5=l2, s6=l3, s7=l4,
    // s8..10=l8..10, s11=l11, s12,13=l12,13
    const int pbs = (((tid >> 3) & 1) << 1) | (((tid >> 5) & 1) << 2) |
                    (((tid >> 6) & 1) << 3) | (tid & 16) | ((tid & 1) << 5) |
                    (((tid >> 1) & 1) << 6) | (((tid >> 2) & 1) << 7) |
                    ((tid >> 7) << 12);
#pragma unroll
    for (int i = 0; i < 16; ++i) {
      int r = (i & 1) | ((i >> 1) << 2);
      int sl = pbs ^ ((((i >> 1) & 7) << 8) | ((i & 1) << 11));
      int a = (PH2B(sl >> 2) << 2) | (sl & 3);
      hs[a >> 1] = pkh(v[r], v[r | 2]);
    }
  }
  __syncthreads();

  // ---- HS3: v = {l7,l5 | rr=l0,l1,l6}: chain C(l7,l6); store ----
  {
    const int pbb = ((tid & 7) << 3) | (((tid >> 3) & 7) << 6) | (((tid >> 6) & 7) << 9);
#pragma unroll
    for (int rr = 0; rr < 8; ++rr) uh4(hs2[PH2B(pbb | rr)], v + 4 * rr);
  }
  cnot32<0, 4>(v);
#pragma unroll
  for (int i = 0; i < 8; ++i) {              // i = {r0(l7), r1(l5), r4(l6)}
    int r0 = i & 1, r1 = (i >> 1) & 1, rh = (i >> 2) & 1;
    int c = r0 | (r1 << 1) | (rh << 4);
    int gidx = (tid & 7) | (r1 << 3) | (t << 4) |
               ((rh | (r0 << 1) | (((tid >> 3) & 0x3F) << 2)) << 11);
    uint2 o; o.x = pkh(v[c], v[c + 4]); o.y = pkh(v[c + 8], v[c + 12]);
    gb[gidx] = o;
  }
}

// ---------------- final H pass + measurement ----------------
__global__ __launch_bounds__(512, 4) void k_Hfin(const float* __restrict__ w,
                                                 unsigned long long stp,
                                                 float* __restrict__ partial) {
  __shared__ __align__(16) unsigned hs[8192];
  uint2* hs2 = reinterpret_cast<uint2*>(hs);
  float* red = reinterpret_cast<float*>(hs);          // reused post-sweeps
  const int tid = threadIdx.x, lane = tid & 63;
  const int bid = blockIdx.x;
  const int b = (bid & 7) >> 1;
  const int t = ((bid >> 3) << 1) | (bid & 1);
  float cv = 1.f, sv = 0.f;
  if (lane < NQ) sincosf(0.5f * w[lane], &sv, &cv);
  const uint2* gb = reinterpret_cast<const uint2*>(stp) + ((size_t)b << 19);
  float v[32];

  // ---- HS1f: wrap; RY q20,q0,q1,q2 ----
#pragma unroll
  for (int rr = 0; rr < 8; ++rr) ld4(gb, GH(A1), v + 4 * rr);
  cnot32<0, 4>(v);
  ry32<0>(v, SHC(20)); ry32<4>(v, SHC(0)); ry32<3>(v, SHC(1)); ry32<2>(v, SHC(2));
  WR_SIGMA2(hs, v);
  __syncthreads();

  // ---- HS2f: v = {l11,l7 | rr=l8,l9,l10}: RY q3..q6; measure ----
  RD_SIGMA2(hs2, v);
  __syncthreads();   // all LDS reads done; hs reused for reduction below
  ry32<4>(v, SHC(3)); ry32<3>(v, SHC(4)); ry32<2>(v, SHC(5)); ry32<1>(v, SHC(6));

  // v bits: 0=l11(q2), 1=l7(q6), 2=l8(q5), 3=l9(q4), 4=l10(q3)
  float S = 0, aq2 = 0, aq6 = 0, aq5 = 0, aq4 = 0, aq3 = 0;
#pragma unroll
  for (int r = 0; r < 32; ++r) {
    float p = v[r] * v[r];
    S += p;
    aq2 += (r & 1)  ? -p : p;
    aq6 += (r & 2)  ? -p : p;
    aq5 += (r & 4)  ? -p : p;
    aq4 += (r & 8)  ? -p : p;
    aq3 += (r & 16) ? -p : p;
  }
  float a21[21];
  a21[2] = aq2; a21[6] = aq6; a21[5] = aq5; a21[4] = aq4; a21[3] = aq3;
  a21[18] = (tid & 1)   ? -S : S;
  a21[17] = (tid & 2)   ? -S : S;
  a21[16] = (tid & 4)   ? -S : S;
  a21[15] = (tid & 8)   ? -S : S;
  a21[7]  = (tid & 16)  ? -S : S;
  a21[20] = (tid & 32)  ? -S : S;
  a21[19] = (tid & 64)  ? -S : S;
  a21[1]  = (tid & 128) ? -S : S;
  a21[0]  = (tid & 256) ? -S : S;
  a21[14] = (t & 1)  ? -S : S;     // t bits = g6..g12 -> q14..q8
  a21[13] = (t & 2)  ? -S : S;
  a21[12] = (t & 4)  ? -S : S;
  a21[11] = (t & 8)  ? -S : S;
  a21[10] = (t & 16) ? -S : S;
  a21[9]  = (t & 32) ? -S : S;
  a21[8]  = (t & 64) ? -S : S;

  const int wv = tid >> 6;
#pragma unroll
  for (int q = 0; q < 21; ++q) {
    float val = a21[q];
    val += __shfl_down(val, 32);
    val += __shfl_down(val, 16);
    val += __shfl_down(val, 8);
    val += __shfl_down(val, 4);
    val += __shfl_down(val, 2);
    val += __shfl_down(val, 1);
    if (lane == 0) red[q * 8 + wv] = val;
  }
  __syncthreads();
  if (tid < NQ) {
    float sum = 0.f;
#pragma unroll
    for (int k = 0; k < 8; ++k) sum += red[tid * 8 + k];
    partial[((b << 7) | t) * NQ + tid] = sum;
  }
}

// ---------------- deterministic final reduction (1 block x 672) ----------------
__global__ void k_red(const float* __restrict__ partial, float* __restrict__ out) {
  __shared__ float red[84][8];
  const int tid = threadIdx.x;
  const int pair = tid >> 3, k8 = tid & 7;
  if (pair < 84) {
    int b = pair / NQ, q = pair % NQ;
    float sum = 0.f;
#pragma unroll
    for (int i = 0; i < 16; ++i) sum += partial[(b * 128 + k8 * 16 + i) * NQ + q];
    red[pair][k8] = sum;
  }
  __syncthreads();
  if (tid < 84) {
    float sum = 0.f;
#pragma unroll
    for (int k = 0; k < 8; ++k) sum += red[tid][k];
    out[tid] = sum;     // tid == b*21 + q
  }
}

extern "C" void kernel_launch(void* const* d_in, const int* in_sizes, int n_in,
                              void* d_out, int out_size, void* d_ws, size_t ws_size,
                              hipStream_t stream) {
  const float* x = (const float*)d_in[0];   // (4,21) f32
  const float* w = (const float*)d_in[1];   // (3,21) f32
  float* out = (float*)d_out;               // (4,21) f32
  unsigned long long stp = (unsigned long long)d_ws;            // 16 MB fp16 state
  float* partial = (float*)((char*)d_ws + (((size_t)4 << 21) * 2));  // 512*21 f32
  if (ws_size < ((size_t)4 << 21) * 2 + 512 * NQ * 4) return;

  dim3 grid(512), blk(512);
  k_L<true> <<<grid, blk, 0, stream>>>(x, w +  0, stp);
  k_H       <<<grid, blk, 0, stream>>>(w +  0, stp);
  k_L<false><<<grid, blk, 0, stream>>>(nullptr, w + 21, stp);
  k_H       <<<grid, blk, 0, stream>>>(w + 21, stp);
  k_L<false><<<grid, blk, 0, stream>>>(nullptr, w + 42, stp);
  k_Hfin    <<<grid, blk, 0, stream>>>(w + 42, stp, partial);
  k_red     <<<1, dim3(672), 0, stream>>>(partial, out);
}

// Round 12
// 96.934 us; speedup vs baseline: 1.3533x; 1.0052x over previous
//
#include <hip/hip_runtime.h>
#include <hip/hip_fp16.h>

// 21-qubit batched (B=4) state-vector simulator, 6 split passes + k_red.
// R12: R11 (fp16 LDS tiles, f32 compute) + ping-pong LDS double-buffer:
// each round-trip writes the OTHER 32KB buffer, deleting the read-drain
// barrier (24 -> 16 barriers/circuit). 64KB LDS total -> occupancy unchanged
// (2 blocks/CU, 4 waves/SIMD). Sweep algebra identical to R11/R8 (verified).
// fp16 global state, XCD batch affinity. Qubit q <-> g-bit (20-q).

#define NQ 21
#define SHC(q) __shfl(cv, (q)), __shfl(sv, (q))

__device__ __forceinline__ int PH2B(int blk) {        // granule swizzle
  return blk ^ ((blk >> 3) & 7) ^ ((blk >> 6) & 7);
}

template<int Q>
__device__ __forceinline__ void ry32(float* v, float c, float s) {
#pragma unroll
  for (int k = 0; k < 16; ++k) {
    int l0 = ((k >> Q) << (Q + 1)) | (k & ((1 << Q) - 1));
    int l1 = l0 | (1 << Q);
    float a0 = v[l0], a1 = v[l1];
    v[l0] = c * a0 - s * a1;
    v[l1] = s * a0 + c * a1;
  }
}

template<int C, int T>
__device__ __forceinline__ void cnot32(float* v) {
  constexpr int lo = (C < T) ? C : T;
  constexpr int hi = (C < T) ? T : C;
#pragma unroll
  for (int k = 0; k < 8; ++k) {
    int i1 = ((k >> lo) << (lo + 1)) | (k & ((1 << lo) - 1));
    int i2 = ((i1 >> hi) << (hi + 1)) | (i1 & ((1 << hi) - 1));
    int a = i2 | (1 << C);
    int b = a | (1 << T);
    float tmp = v[a]; v[a] = v[b]; v[b] = tmp;
  }
}

// fp16 helpers: 4 amps (8B) <-> 4 f32 regs ; 2 amps <-> 1 uint
__device__ __forceinline__ void uh4(uint2 u, float* d) {
  __half2 h0 = *reinterpret_cast<__half2*>(&u.x);
  __half2 h1 = *reinterpret_cast<__half2*>(&u.y);
  float2 f0 = __half22float2(h0), f1 = __half22float2(h1);
  d[0] = f0.x; d[1] = f0.y; d[2] = f1.x; d[3] = f1.y;
}
__device__ __forceinline__ void ld4(const uint2* __restrict__ g, int idx, float* dst) {
  uh4(g[idx], dst);
}
__device__ __forceinline__ unsigned pkh(float a, float b) {
  __half2 h = __floats2half2_rn(a, b);
  return *reinterpret_cast<unsigned*>(&h);
}

#define A1 (tid | (rr << 9))
#define GH(l4) (((l4) & 0xF) | (t << 4) | (((l4) >> 4) << 11))

// sigma2-style write (S1/HS1): pairs over v-bit2 (b32 writes)
#define WR_SIGMA2(hs, v)                                                       \
  {                                                                            \
    const int pbs = (((tid >> 5) & 1) << 1) | ((tid & 31) << 2) |              \
                    (((tid >> 6) & 7) << 9);                                   \
    _Pragma("unroll") for (int i = 0; i < 16; ++i) {                           \
      int r = (i & 3) | ((i >> 2) << 3);                                       \
      int sl = pbs ^ (((i & 3) << 7) | ((i >> 2) << 12));                      \
      int a = (PH2B(sl >> 2) << 2) | (sl & 3);                                 \
      (hs)[a >> 1] = pkh((v)[r], (v)[r | 4]);                                  \
    }                                                                          \
  }

// sigma2-style read (S2/HS2): granule (4 amps) = uint2 b64 read + unpack
#define RD_SIGMA2(hs2, v)                                                      \
  {                                                                            \
    const int pbb = (tid & 31) | (((tid >> 5) & 3) << 5) |                     \
                    (((tid >> 7) & 3) << 10);                                  \
    _Pragma("unroll") for (int rr = 0; rr < 8; ++rr)                           \
      uh4((hs2)[PH2B(pbb ^ (rr << 7))], (v) + 4 * rr);                         \
  }

// ---------------- L pass: tile = bits 0..13, t = bits 14..20 ----------------
template<bool INIT>
__global__ __launch_bounds__(512, 4) void k_L(const float* __restrict__ x,
                                              const float* __restrict__ w,
                                              unsigned long long stp) {
  __shared__ __align__(16) unsigned hsA[8192];        // 32 KB
  __shared__ __align__(16) unsigned hsB[8192];        // 32 KB
  uint2* hsA2 = reinterpret_cast<uint2*>(hsA);
  uint2* hsB2 = reinterpret_cast<uint2*>(hsB);
  const int tid = threadIdx.x, lane = tid & 63;
  const int bid = blockIdx.x;
  const int b = (bid & 7) >> 1;                       // XCD-pair affinity
  const int t = ((bid >> 3) << 1) | (bid & 1);
  float cv = 1.f, sv = 0.f;
  if (lane < NQ) sincosf(0.5f * w[lane], &sv, &cv);
  uint2* g2 = reinterpret_cast<uint2*>(stp) + ((size_t)b << 19) + ((size_t)t << 12);
  float v[32];

  // ---- S1: v = {amp0,amp1 | rr=amp11,12,13}: C(13,12),(12,11); RY q7,q8 ----
  if (INIT) {
    float cx = 1.f, sx = 0.f;
    if (lane < NQ) sincosf(0.5f * x[b * NQ + lane], &sx, &cx);
    float Qp = 1.f;
#pragma unroll
    for (int i = 0; i < 9; ++i) {            // tid bit i -> g(2+i) -> qubit 18-i
      float cq = __shfl(cx, 18 - i), sq = __shfl(sx, 18 - i);
      Qp *= ((tid >> i) & 1) ? sq : cq;
    }
    float hfac[2];
#pragma unroll
    for (int bb = 0; bb < 2; ++bb) {         // g13 = bb, h = g[13..20]
      int h = (t << 1) | bb;
      int h0 = h ^ (h >> 1);                 // pre-image of high chain
      float p = 1.f;
#pragma unroll
      for (int j = 0; j < 8; ++j) {
        float cq = __shfl(cx, 7 - j), sq = __shfl(sx, 7 - j);
        p *= ((h0 >> j) & 1) ? sq : cq;
      }
      hfac[bb] = p;
    }
    float c20 = __shfl(cx, 20), s20 = __shfl(sx, 20);
    float c19 = __shfl(cx, 19), s19 = __shfl(sx, 19);
    float c9  = __shfl(cx, 9),  s9  = __shfl(sx, 9);
    float c8  = __shfl(cx, 8),  s8  = __shfl(sx, 8);
    float w0t[4], w1t[4];
#pragma unroll
    for (int i = 0; i < 4; ++i) {
      w0t[i] = ((i & 1) ? s20 : c20) * ((i & 2) ? s19 : c19);  // amps 0,1
      w1t[i] = ((i & 1) ? s9  : c9 ) * ((i & 2) ? s8  : c8 );  // amps 11,12
    }
#pragma unroll
    for (int r = 0; r < 32; ++r)
      v[r] = hfac[(r >> 4) & 1] * w1t[(r >> 2) & 3] * w0t[r & 3] * Qp;
  } else {
#pragma unroll
    for (int rr = 0; rr < 8; ++rr) ld4(g2, A1, v + 4 * rr);
  }
  cnot32<4, 3>(v); cnot32<3, 2>(v);
  ry32<4>(v, SHC(7)); ry32<3>(v, SHC(8));
  WR_SIGMA2(hsA, v);                         // -> A ; s0=amp11
  __syncthreads();

  // ---- S2: v = {amp11,amp7 | rr=amp8,9,10}: C(11,10),(10,9),(9,8),(8,7) ----
  RD_SIGMA2(hsA2, v);
  cnot32<0, 4>(v); cnot32<4, 3>(v); cnot32<3, 2>(v); cnot32<2, 1>(v);
  ry32<0>(v, SHC(9)); ry32<4>(v, SHC(10)); ry32<3>(v, SHC(11)); ry32<2>(v, SHC(12));
  {
    // sigma3 -> B: s0=amp7(pair), s1=amp3, s2=amp4, s3=amp5, s4=amp6, s5=amp2,
    // s6=amp1, s7=amp0, s8..10=amp8..10, s11=amp11, s12,13=amp12,13
    const int pbs = (tid & 0x1E) | ((tid & 1) << 5) | (tid & 0x40) |
                    (((tid >> 5) & 1) << 7) | ((tid >> 7) << 12);
#pragma unroll
    for (int i = 0; i < 16; ++i) {
      int r = (i & 1) | ((i >> 1) << 2);
      int sl = pbs ^ ((((i >> 1) & 7) << 8) | ((i & 1) << 11));
      int a = (PH2B(sl >> 2) << 2) | (sl & 3);
      hsB[a >> 1] = pkh(v[r], v[r | 2]);
    }
  }
  __syncthreads();

  // ---- S3: v = {amp7,amp3 | rr=amp4,5,6}: C(7,6),(6,5),(5,4),(4,3) ----
  {
    const int pbb = ((tid & 7) << 3) | (((tid >> 3) & 7) << 6) | (((tid >> 6) & 7) << 9);
#pragma unroll
    for (int rr = 0; rr < 8; ++rr) uh4(hsB2[PH2B(pbb | rr)], v + 4 * rr);
  }
  cnot32<0, 4>(v); cnot32<4, 3>(v); cnot32<3, 2>(v); cnot32<2, 1>(v);
  ry32<0>(v, SHC(13)); ry32<4>(v, SHC(14)); ry32<3>(v, SHC(15)); ry32<2>(v, SHC(16));
  {
    // identity'' -> A: s0=amp3, s1=amp4 (quads), s2=amp0, s3=amp1, s4=amp2,
    // s5=amp5, s6=amp6, s7=amp7, s8..13=amp8..13  (b64 quad writes)
    const int pbs = (((tid >> 2) & 1) << 2) | (((tid >> 1) & 1) << 3) |
                    ((tid & 1) << 4) | (((tid >> 3) & 7) << 8) |
                    (((tid >> 6) & 7) << 11);
#pragma unroll
    for (int i = 0; i < 8; ++i) {
      int r = (i & 1) | ((i >> 1) << 3);
      int sl = pbs ^ ((((i >> 1) & 1) << 5) | (((i >> 2) & 1) << 6) | ((i & 1) << 7));
      uint2 o; o.x = pkh(v[r], v[r | 2]); o.y = pkh(v[r | 4], v[r | 6]);
      hsA2[PH2B(sl >> 2)] = o;
    }
  }
  __syncthreads();

  // ---- S4: v = {amp3,amp4 | rr=amp0,1,2}: C(3,2),(2,1),(1,0); RY q17..q19 ----
  {
    const int pbb = tid << 3;
#pragma unroll
    for (int rr = 0; rr < 8; ++rr) uh4(hsA2[PH2B(pbb | rr)], v + 4 * rr);
  }
  cnot32<0, 4>(v); cnot32<4, 3>(v); cnot32<3, 2>(v);
  ry32<0>(v, SHC(17)); ry32<4>(v, SHC(18)); ry32<3>(v, SHC(19));
  {
    uint4* g4o = reinterpret_cast<uint4*>(g2);
#pragma unroll
    for (int i = 0; i < 4; ++i) {            // i = {a3, a4}
      int c = (i & 1) | ((i >> 1) << 1);
      uint4 o;
      o.x = pkh(v[c], v[c + 4]);   o.y = pkh(v[c + 8], v[c + 12]);
      o.z = pkh(v[c + 16], v[c + 20]); o.w = pkh(v[c + 24], v[c + 28]);
      g4o[(i & 1) | ((i >> 1) << 1) | (tid << 2)] = o;
    }
  }
}

// ---------------- H pass: tile = {g0..g5, g13..g20} (l0..l5, l6..l13) ----------------
__global__ __launch_bounds__(512, 4) void k_H(const float* __restrict__ w,
                                              unsigned long long stp) {
  __shared__ __align__(16) unsigned hsA[8192];
  __shared__ __align__(16) unsigned hsB[8192];
  uint2* hsA2 = reinterpret_cast<uint2*>(hsA);
  uint2* hsB2 = reinterpret_cast<uint2*>(hsB);
  const int tid = threadIdx.x, lane = tid & 63;
  const int bid = blockIdx.x;
  const int b = (bid & 7) >> 1;
  const int t = ((bid >> 3) << 1) | (bid & 1);
  float cv = 1.f, sv = 0.f;
  if (lane < NQ) sincosf(0.5f * w[lane], &sv, &cv);
  uint2* gb = reinterpret_cast<uint2*>(stp) + ((size_t)b << 19);
  float v[32];

  // ---- HS1: v = {l0,l1 | rr=l11,l12,l13}: wrap C(g0,g20); RY q20,q0,q1,q2;
  //      next-layer chain C(l13,l12),(l12,l11) ----
#pragma unroll
  for (int rr = 0; rr < 8; ++rr) ld4(gb, GH(A1), v + 4 * rr);
  cnot32<0, 4>(v);
  ry32<0>(v, SHC(20)); ry32<4>(v, SHC(0)); ry32<3>(v, SHC(1)); ry32<2>(v, SHC(2));
  cnot32<4, 3>(v); cnot32<3, 2>(v);
  WR_SIGMA2(hsA, v);                         // -> A ; s0=l11
  __syncthreads();

  // ---- HS2: v = {l11,l7 | rr=l8,l9,l10}: RY q3..q6; chain C(l11,l10)..(l8,l7) ----
  RD_SIGMA2(hsA2, v);
  ry32<4>(v, SHC(3)); ry32<3>(v, SHC(4)); ry32<2>(v, SHC(5)); ry32<1>(v, SHC(6));
  cnot32<0, 4>(v); cnot32<4, 3>(v); cnot32<3, 2>(v); cnot32<2, 1>(v);
  {
    // sigma3H -> B: s0=l7(pair), s1=l5, s2=l0, s3=l1, s4=l6, s5=l2, s6=l3,
    // s7=l4, s8..10=l8..10, s11=l11, s12,13=l12,13
    const int pbs = (((tid >> 3) & 1) << 1) | (((tid >> 5) & 1) << 2) |
                    (((tid >> 6) & 1) << 3) | (tid & 16) | ((tid & 1) << 5) |
                    (((tid >> 1) & 1) << 6) | (((tid >> 2) & 1) << 7) |
                    ((tid >> 7) << 12);
#pragma unroll
    for (int i = 0; i < 16; ++i) {
      int r = (i & 1) | ((i >> 1) << 2);
      int sl = pbs ^ ((((i >> 1) & 7) << 8) | ((i & 1) << 11));
      int a = (PH2B(sl >> 2) << 2) | (sl & 3);
      hsB[a >> 1] = pkh(v[r], v[r | 2]);
    }
  }
  __syncthreads();

  // ---- HS3: v = {l7,l5 | rr=l0,l1,l6}: chain C(l7,l6); store ----
  {
    const int pbb = ((tid & 7) << 3) | (((tid >> 3) & 7) << 6) | (((tid >> 6) & 7) << 9);
#pragma unroll
    for (int rr = 0; rr < 8; ++rr) uh4(hsB2[PH2B(pbb | rr)], v + 4 * rr);
  }
  cnot32<0, 4>(v);
#pragma unroll
  for (int i = 0; i < 8; ++i) {              // i = {r0(l7), r1(l5), r4(l6)}
    int r0 = i & 1, r1 = (i >> 1) & 1, rh = (i >> 2) & 1;
    int c = r0 | (r1 << 1) | (rh << 4);
    int gidx = (tid & 7) | (r1 << 3) | (t << 4) |
               ((rh | (r0 << 1) | (((tid >> 3) & 0x3F) << 2)) << 11);
    uint2 o; o.x = pkh(v[c], v[c + 4]); o.y = pkh(v[c + 8], v[c + 12]);
    gb[gidx] = o;
  }
}

// ---------------- final H pass + measurement ----------------
__global__ __launch_bounds__(512, 4) void k_Hfin(const float* __restrict__ w,
                                                 unsigned long long stp,
                                                 float* __restrict__ partial) {
  __shared__ __align__(16) unsigned hsA[8192];
  __shared__ __align__(16) unsigned hsB[8192];
  uint2* hsA2 = reinterpret_cast<uint2*>(hsA);
  float* red = reinterpret_cast<float*>(hsB);         // reduction in B (no hazard)
  const int tid = threadIdx.x, lane = tid & 63;
  const int bid = blockIdx.x;
  const int b = (bid & 7) >> 1;
  const int t = ((bid >> 3) << 1) | (bid & 1);
  float cv = 1.f, sv = 0.f;
  if (lane < NQ) sincosf(0.5f * w[lane], &sv, &cv);
  const uint2* gb = reinterpret_cast<const uint2*>(stp) + ((size_t)b << 19);
  float v[32];

  // ---- HS1f: wrap; RY q20,q0,q1,q2 ----
#pragma unroll
  for (int rr = 0; rr < 8; ++rr) ld4(gb, GH(A1), v + 4 * rr);
  cnot32<0, 4>(v);
  ry32<0>(v, SHC(20)); ry32<4>(v, SHC(0)); ry32<3>(v, SHC(1)); ry32<2>(v, SHC(2));
  WR_SIGMA2(hsA, v);
  __syncthreads();

  // ---- HS2f: v = {l11,l7 | rr=l8,l9,l10}: RY q3..q6; measure ----
  RD_SIGMA2(hsA2, v);
  ry32<4>(v, SHC(3)); ry32<3>(v, SHC(4)); ry32<2>(v, SHC(5)); ry32<1>(v, SHC(6));

  // v bits: 0=l11(q2), 1=l7(q6), 2=l8(q5), 3=l9(q4), 4=l10(q3)
  float S = 0, aq2 = 0, aq6 = 0, aq5 = 0, aq4 = 0, aq3 = 0;
#pragma unroll
  for (int r = 0; r < 32; ++r) {
    float p = v[r] * v[r];
    S += p;
    aq2 += (r & 1)  ? -p : p;
    aq6 += (r & 2)  ? -p : p;
    aq5 += (r & 4)  ? -p : p;
    aq4 += (r & 8)  ? -p : p;
    aq3 += (r & 16) ? -p : p;
  }
  float a21[21];
  a21[2] = aq2; a21[6] = aq6; a21[5] = aq5; a21[4] = aq4; a21[3] = aq3;
  a21[18] = (tid & 1)   ? -S : S;
  a21[17] = (tid & 2)   ? -S : S;
  a21[16] = (tid & 4)   ? -S : S;
  a21[15] = (tid & 8)   ? -S : S;
  a21[7]  = (tid & 16)  ? -S : S;
  a21[20] = (tid & 32)  ? -S : S;
  a21[19] = (tid & 64)  ? -S : S;
  a21[1]  = (tid & 128) ? -S : S;
  a21[0]  = (tid & 256) ? -S : S;
  a21[14] = (t & 1)  ? -S : S;     // t bits = g6..g12 -> q14..q8
  a21[13] = (t & 2)  ? -S : S;
  a21[12] = (t & 4)  ? -S : S;
  a21[11] = (t & 8)  ? -S : S;
  a21[10] = (t & 16) ? -S : S;
  a21[9]  = (t & 32) ? -S : S;
  a21[8]  = (t & 64) ? -S : S;

  const int wv = tid >> 6;
#pragma unroll
  for (int q = 0; q < 21; ++q) {
    float val = a21[q];
    val += __shfl_down(val, 32);
    val += __shfl_down(val, 16);
    val += __shfl_down(val, 8);
    val += __shfl_down(val, 4);
    val += __shfl_down(val, 2);
    val += __shfl_down(val, 1);
    if (lane == 0) red[q * 8 + wv] = val;
  }
  __syncthreads();
  if (tid < NQ) {
    float sum = 0.f;
#pragma unroll
    for (int k = 0; k < 8; ++k) sum += red[tid * 8 + k];
    partial[((b << 7) | t) * NQ + tid] = sum;
  }
}

// ---------------- deterministic final reduction (1 block x 672) ----------------
__global__ void k_red(const float* __restrict__ partial, float* __restrict__ out) {
  __shared__ float red[84][8];
  const int tid = threadIdx.x;
  const int pair = tid >> 3, k8 = tid & 7;
  if (pair < 84) {
    int b = pair / NQ, q = pair % NQ;
    float sum = 0.f;
#pragma unroll
    for (int i = 0; i < 16; ++i) sum += partial[(b * 128 + k8 * 16 + i) * NQ + q];
    red[pair][k8] = sum;
  }
  __syncthreads();
  if (tid < 84) {
    float sum = 0.f;
#pragma unroll
    for (int k = 0; k < 8; ++k) sum += red[tid][k];
    out[tid] = sum;     // tid == b*21 + q
  }
}

extern "C" void kernel_launch(void* const* d_in, const int* in_sizes, int n_in,
                              void* d_out, int out_size, void* d_ws, size_t ws_size,
                              hipStream_t stream) {
  const float* x = (const float*)d_in[0];   // (4,21) f32
  const float* w = (const float*)d_in[1];   // (3,21) f32
  float* out = (float*)d_out;               // (4,21) f32
  unsigned long long stp = (unsigned long long)d_ws;            // 16 MB fp16 state
  float* partial = (float*)((char*)d_ws + (((size_t)4 << 21) * 2));  // 512*21 f32
  if (ws_size < ((size_t)4 << 21) * 2 + 512 * NQ * 4) return;

  dim3 grid(512), blk(512);
  k_L<true> <<<grid, blk, 0, stream>>>(x, w +  0, stp);
  k_H       <<<grid, blk, 0, stream>>>(w +  0, stp);
  k_L<false><<<grid, blk, 0, stream>>>(nullptr, w + 21, stp);
  k_H       <<<grid, blk, 0, stream>>>(w + 21, stp);
  k_L<false><<<grid, blk, 0, stream>>>(nullptr, w + 42, stp);
  k_Hfin    <<<grid, blk, 0, stream>>>(w + 42, stp, partial);
  k_red     <<<1, dim3(672), 0, stream>>>(partial, out);
}